// Round 1
// baseline (102.255 us; speedup 1.0000x reference)
//
#include <hip/hip_runtime.h>
#include <hip/hip_fp16.h>
#include <hip/hip_bf16.h>

#define NB 256
#define IN_F 1024
#define BEX 256
#define KD 16
#define NJ 4096
#define OUT_F 1280

typedef short bf16x8 __attribute__((ext_vector_type(8)));
typedef float f32x4 __attribute__((ext_vector_type(4)));
typedef _Float16 h2 __attribute__((ext_vector_type(2)));

__device__ inline unsigned short f2bf(float f) {
    __hip_bfloat16 h = __float2bfloat16(f);
    return *reinterpret_cast<unsigned short*>(&h);
}

union U8 { float4 f4[2]; h2 h[8]; };

// ---- kernel 1: x f32 -> out[:, :1024] copy + x_bf (bf16) ----
// grid 256 (one row each), block 256. One float4 per thread.
__global__ __launch_bounds__(256) void k_prep(const float* __restrict__ x,
                                              float* __restrict__ out,
                                              unsigned short* __restrict__ x_bf) {
    const int r = blockIdx.x, t = threadIdx.x;
    float4 v = *(const float4*)(x + (size_t)r * IN_F + t * 4);
    *(float4*)(out + (size_t)r * OUT_F + t * 4) = v;
    ushort4 o;
    o.x = f2bf(v.x); o.y = f2bf(v.y); o.z = f2bf(v.z); o.w = f2bf(v.w);
    *(ushort4*)(x_bf + (size_t)r * IN_F + t * 4) = o;
}

// ---- kernel 2: fused per-b GEMM slice + pairwise + column write ----
// grid 256 (one b each), block 512 (8 waves).
// Phase 1: T[:, b*16..+16) (1024x16 f32) -> TsT LDS [16][1024] bf16, XOR-swizzled
//          chunks: element (kp, i) at ushort idx kp*1024 + (((i>>3)^(kp&7))<<3) + (i&7)
// Phase 2: M[n, kp] = sum_i x[n,i] * Ts[i,kp]; wave w owns rows [w*32, w*32+32).
//          A-frag (lane l: row l&15, k = (l>>4)*8+e) loaded DIRECT from global x_bf.
//          B-frag (lane l: row kp=l&15, k = (l>>4)*8+e) via one swizzled ds_read_b128.
// Phase 3: rows[256][16] fp16 in LDS (C/D layout: col=l&15, row=(l>>4)*4+r).
// Phase 4: pairwise, identical structure to proven kernel: thread (qg=t&63, ms=t>>6)
//          does q = 4qg..+3 vs m in [ms*32, +32); fdot2 L1, exp, part[256][8].
// Phase 5: in-block reduce, out[q,1024+b] = sum - 1 (self term), no atomics.
__global__ __launch_bounds__(512) void k_fused(const float* __restrict__ T,
                                               const unsigned short* __restrict__ x_bf,
                                               float* __restrict__ out) {
    __shared__ unsigned short TsT[16 * 1024];  // 32 KB
    __shared__ __half rows[NB * KD];           // 8 KB
    __shared__ float part[NB * 8];             // 8 KB

    const int b = blockIdx.x;
    const int t = threadIdx.x;
    const int w = t >> 6, l = t & 63;

    // ---- phase 1: load + transpose + convert T slice ----
    #pragma unroll
    for (int p = 0; p < 8; ++p) {
        const int g = p * 512 + t;          // [0, 4096) float4s
        const int i = g >> 2, c4 = g & 3;   // row i of Ts, 4-col group
        float4 v = *(const float4*)(T + (size_t)i * NJ + b * KD + c4 * 4);
        const float f[4] = {v.x, v.y, v.z, v.w};
        #pragma unroll
        for (int jj = 0; jj < 4; ++jj) {
            const int kp = c4 * 4 + jj;
            TsT[kp * 1024 + (((i >> 3) ^ (kp & 7)) << 3) + (i & 7)] = f2bf(f[jj]);
        }
    }
    __syncthreads();

    // ---- phase 2: GEMM, 32 K-steps of 32 ----
    f32x4 acc0 = {0.f, 0.f, 0.f, 0.f}, acc1 = {0.f, 0.f, 0.f, 0.f};
    const int kp = l & 15;
    const int lr = l >> 4;
    const unsigned short* ap = x_bf + (size_t)(w * 32 + kp) * IN_F + lr * 8;
    const unsigned short* Tb = &TsT[kp * 1024];
    #pragma unroll 8
    for (int s = 0; s < 32; ++s) {
        const int ch = s * 4 + lr;                               // chunk = i0/8 + lr
        bf16x8 bf = *(const bf16x8*)&Tb[(ch ^ (kp & 7)) << 3];   // swizzled read
        bf16x8 a0 = *(const bf16x8*)(ap + s * 32);
        bf16x8 a1 = *(const bf16x8*)(ap + 16 * IN_F + s * 32);
        acc0 = __builtin_amdgcn_mfma_f32_16x16x32_bf16(a0, bf, acc0, 0, 0, 0);
        acc1 = __builtin_amdgcn_mfma_f32_16x16x32_bf16(a1, bf, acc1, 0, 0, 0);
    }

    // ---- phase 3: write M slice to rows[] as fp16 ----
    #pragma unroll
    for (int r = 0; r < 4; ++r) {
        const int n0 = w * 32 + lr * 4 + r;
        rows[n0 * KD + kp] = __float2half(acc0[r]);
        rows[(n0 + 16) * KD + kp] = __float2half(acc1[r]);
    }
    __syncthreads();

    // ---- phase 4: pairwise ----
    const int qg = l, ms = w;
    U8 q[4];
    #pragma unroll
    for (int r = 0; r < 4; ++r) {
        const __half* qp = rows + (qg * 4 + r) * KD;
        q[r].f4[0] = *(const float4*)(qp);
        q[r].f4[1] = *(const float4*)(qp + 8);
    }
    const h2 one = {(_Float16)1.0f, (_Float16)1.0f};
    float e[4] = {0.f, 0.f, 0.f, 0.f};

    #pragma unroll 2
    for (int m = 0; m < 32; ++m) {
        U8 p;
        const __half* rp = rows + (ms * 32 + m) * KD;   // wave-uniform -> broadcast
        p.f4[0] = *(const float4*)(rp);
        p.f4[1] = *(const float4*)(rp + 8);
        #pragma unroll
        for (int r = 0; r < 4; ++r) {
            float l0 = 0.f, l1 = 0.f;
            #pragma unroll
            for (int i = 0; i < 8; i += 2) {
                h2 d0 = q[r].h[i] - p.h[i];
                h2 d1 = q[r].h[i + 1] - p.h[i + 1];
                unsigned u0 = (*(unsigned*)&d0) & 0x7FFF7FFFu;
                unsigned u1 = (*(unsigned*)&d1) & 0x7FFF7FFFu;
                l0 = __builtin_amdgcn_fdot2(*(h2*)&u0, one, l0, false);
                l1 = __builtin_amdgcn_fdot2(*(h2*)&u1, one, l1, false);
            }
            e[r] += __expf(-(l0 + l1));
        }
    }

    #pragma unroll
    for (int r = 0; r < 4; ++r)
        part[(qg * 4 + r) * 8 + ms] = e[r];
    __syncthreads();

    // ---- phase 5: reduce over 8 m-groups, subtract self term, write column b ----
    if (t < NB) {
        float4 pa = ((const float4*)part)[t * 2];
        float4 pb = ((const float4*)part)[t * 2 + 1];
        out[(size_t)t * OUT_F + IN_F + b] =
            (pa.x + pa.y + pa.z + pa.w + pb.x + pb.y + pb.z + pb.w) - 1.0f;
    }
}

extern "C" void kernel_launch(void* const* d_in, const int* in_sizes, int n_in,
                              void* d_out, int out_size, void* d_ws, size_t ws_size,
                              hipStream_t stream) {
    const float* x = (const float*)d_in[0];   // (256, 1024) f32
    const float* T = (const float*)d_in[1];   // (1024, 256, 16) f32 = (1024, 4096)
    float* out = (float*)d_out;               // (256, 1280) f32

    unsigned short* x_bf = (unsigned short*)d_ws;   // 512 KB

    k_prep<<<dim3(256), dim3(256), 0, stream>>>(x, out, x_bf);
    k_fused<<<dim3(256), dim3(512), 0, stream>>>(T, x_bf, out);
}

// Round 2
// 90.603 us; speedup vs baseline: 1.1286x; 1.1286x over previous
//
#include <hip/hip_runtime.h>
#include <hip/hip_fp16.h>
#include <hip/hip_bf16.h>

#define NB 256
#define IN_F 1024
#define BEX 256
#define KD 16
#define NJ 4096
#define OUT_F 1280

typedef short bf16x8 __attribute__((ext_vector_type(8)));
typedef float f32x4 __attribute__((ext_vector_type(4)));
typedef _Float16 h2 __attribute__((ext_vector_type(2)));

__device__ inline unsigned short f2bf(float f) {
    __hip_bfloat16 h = __float2bfloat16(f);
    return *reinterpret_cast<unsigned short*>(&h);
}

__device__ inline void cp16(const void* g, void* l) {
    __builtin_amdgcn_global_load_lds((const __attribute__((address_space(1))) void*)g,
                                     (__attribute__((address_space(3))) void*)l, 16, 0, 0);
}

union U8 { float4 f4[2]; h2 h[8]; };

// ---- kernel 1: prep = transpose/convert T  +  copy x / bf16(x) ----
// blocks [0, 4096): transpose 32x32 tile of T (1024x4096 f32) -> Tt (4096x1024 bf16)
// blocks [4096, 4352): row r = bid-4096: out[r,:1024]=x[r], x_bf[r]=bf16(x[r])
// (no out-init needed: pairwise writes its column exclusively, no atomics)
__global__ __launch_bounds__(256) void k_prep(const float* __restrict__ x,
                                              const float* __restrict__ T,
                                              float* __restrict__ out,
                                              unsigned short* __restrict__ x_bf,
                                              unsigned short* __restrict__ Tt) {
    const int bid = blockIdx.x;
    const int t = threadIdx.x;
    if (bid < 4096) {
        __shared__ float tile[32][33];
        const int j0 = (bid & 127) * 32;
        const int i0 = (bid >> 7) * 32;
        {
            const int r = t >> 3, cg = (t & 7) << 2;
            float4 v = *(const float4*)(T + (size_t)(i0 + r) * NJ + j0 + cg);
            tile[r][cg + 0] = v.x; tile[r][cg + 1] = v.y;
            tile[r][cg + 2] = v.z; tile[r][cg + 3] = v.w;
        }
        __syncthreads();
        const int jr = t >> 3, ig = (t & 7) << 2;
        ushort4 o;
        o.x = f2bf(tile[ig + 0][jr]);
        o.y = f2bf(tile[ig + 1][jr]);
        o.z = f2bf(tile[ig + 2][jr]);
        o.w = f2bf(tile[ig + 3][jr]);
        *(ushort4*)(Tt + (size_t)(j0 + jr) * IN_F + i0 + ig) = o;
    } else {
        const int r = bid - 4096;
        float4 v = *(const float4*)(x + (size_t)r * IN_F + t * 4);
        *(float4*)(out + (size_t)r * OUT_F + t * 4) = v;
        ushort4 o;
        o.x = f2bf(v.x); o.y = f2bf(v.y); o.z = f2bf(v.z); o.w = f2bf(v.w);
        *(ushort4*)(x_bf + (size_t)r * IN_F + t * 4) = o;
    }
}

// ---- kernel 2: bf16 MFMA GEMM: M2h[b][n][k] fp16 ---- (unchanged, proven)
__global__ __launch_bounds__(256) void k_gemm(const unsigned short* __restrict__ A,   // [256][1024]
                                              const unsigned short* __restrict__ B,   // [4096][1024]
                                              __half* __restrict__ M2h) {
    __shared__ unsigned short lds[4][64 * 128];   // 64 KB
    const int t = threadIdx.x;
    const int w = t >> 6, l = t & 63;
    const int n0 = blockIdx.y * 64;
    const int j0 = blockIdx.x * 64;

    const unsigned short* aA[4];
    const unsigned short* aB[4];
    int lofs[4];
    #pragma unroll
    for (int p = 0; p < 4; ++p) {
        int s = t + p * 256;
        int r = s >> 4;
        int kg = (s & 15) ^ (r & 15);
        aA[p] = A + (size_t)(n0 + r) * IN_F + kg * 8;
        aB[p] = B + (size_t)(j0 + r) * IN_F + kg * 8;
        lofs[p] = s * 8;
    }

    f32x4 acc[2][2];
    #pragma unroll
    for (int i = 0; i < 2; ++i)
        #pragma unroll
        for (int j = 0; j < 2; ++j)
            acc[i][j] = (f32x4){0.f, 0.f, 0.f, 0.f};

    #pragma unroll
    for (int p = 0; p < 4; ++p) cp16(aA[p], &lds[0][lofs[p]]);
    #pragma unroll
    for (int p = 0; p < 4; ++p) cp16(aB[p], &lds[1][lofs[p]]);

    const int rowA0 = ((w & 1) * 32 + (l & 15)) * 128;
    const int rowA1 = rowA0 + 16 * 128;
    const int rowB0 = (((w >> 1) & 1) * 32 + (l & 15)) * 128;
    const int rowB1 = rowB0 + 16 * 128;

    for (int s = 0; s < 8; ++s) {
        __syncthreads();
        if (s < 7) {
            const int k0 = (s + 1) * 128;
            const int bsel = ((s + 1) & 1) * 2;
            #pragma unroll
            for (int p = 0; p < 4; ++p) cp16(aA[p] + k0, &lds[bsel + 0][lofs[p]]);
            #pragma unroll
            for (int p = 0; p < 4; ++p) cp16(aB[p] + k0, &lds[bsel + 1][lofs[p]]);
        }
        const unsigned short* La = lds[(s & 1) * 2 + 0];
        const unsigned short* Lb = lds[(s & 1) * 2 + 1];
        #pragma unroll
        for (int kk = 0; kk < 4; ++kk) {
            const int kg = kk * 4 + (l >> 4);
            const int ks = (kg ^ (l & 15)) * 8;
            bf16x8 a0 = *(const bf16x8*)&La[rowA0 + ks];
            bf16x8 a1 = *(const bf16x8*)&La[rowA1 + ks];
            bf16x8 b0 = *(const bf16x8*)&Lb[rowB0 + ks];
            bf16x8 b1 = *(const bf16x8*)&Lb[rowB1 + ks];
            acc[0][0] = __builtin_amdgcn_mfma_f32_16x16x32_bf16(a0, b0, acc[0][0], 0, 0, 0);
            acc[0][1] = __builtin_amdgcn_mfma_f32_16x16x32_bf16(a0, b1, acc[0][1], 0, 0, 0);
            acc[1][0] = __builtin_amdgcn_mfma_f32_16x16x32_bf16(a1, b0, acc[1][0], 0, 0, 0);
            acc[1][1] = __builtin_amdgcn_mfma_f32_16x16x32_bf16(a1, b1, acc[1][1], 0, 0, 0);
        }
    }

    const int col = l & 15;
    #pragma unroll
    for (int nt = 0; nt < 2; ++nt) {
        #pragma unroll
        for (int jt = 0; jt < 2; ++jt) {
            const int jc = j0 + ((w >> 1) & 1) * 32 + jt * 16 + col;
            const int bb = jc >> 4;
            const int k = jc & 15;
            __half* base = M2h + (size_t)bb * (NB * KD) + k;
            #pragma unroll
            for (int r = 0; r < 4; ++r) {
                const int n = n0 + (w & 1) * 32 + nt * 16 + (l >> 4) * 4 + r;
                base[n * KD] = __float2half(acc[nt][jt][r]);
            }
        }
    }
}

// ---- kernel 3: symmetric pairwise ----
// grid 256 (one b each), block 512 (8 waves). 4x4 grid of 64x64 pair-tiles;
// off-diag tiles (tj>ti) computed ONCE, exp credited to both q-side (regs) and
// m-side (shfl-reduce over qq -> single-leader LDS +=, race-free by construction).
// Diagonal tiles computed ordered-full (incl. self; -1 at the end).
// rows[] 16B-unit XOR swizzle: unit (2n+h) stored at (2n+h) ^ ((n>>2)&7)
// -> q-row reads (16 distinct rows, stride 128B) drop to 2-way bank access.
__global__ __launch_bounds__(512) void k_pairwise(const __half* __restrict__ M2h,
                                                  float* __restrict__ out) {
    __shared__ __half rows[NB * KD];   // 8 KB
    __shared__ float Sm[NB];           // 1 KB
    __shared__ float part[NB * 8];     // 8 KB
    const int b = blockIdx.x;
    const int t = threadIdx.x;
    const int lane = t & 63, w = t >> 6;
    const int qq = t & 15;     // q subgroup (16 per tile-row, x4 rows each)
    const int mm = t >> 4;     // m pair index 0..31 (2 m-rows each)
    const __half* Mb = M2h + (size_t)b * (NB * KD);

    {
        float4 v = ((const float4*)Mb)[t];            // linear 16B unit t
        ((float4*)rows)[t ^ ((t >> 3) & 7)] = v;      // swizzled placement
    }
    if (t < NB) Sm[t] = 0.f;
    __syncthreads();

    const h2 one = {(_Float16)1.0f, (_Float16)1.0f};

    #pragma unroll
    for (int ti = 0; ti < 4; ++ti) {
        // q rows for this tile-row (16 fp16 each), swizzled ds_read_b128 x2
        U8 q[4];
        #pragma unroll
        for (int r = 0; r < 4; ++r) {
            const int n = ti * 64 + qq * 4 + r;
            const int sw = (n >> 2) & 7;
            q[r].f4[0] = ((const float4*)rows)[(n * 2) ^ sw];
            q[r].f4[1] = ((const float4*)rows)[(n * 2 + 1) ^ sw];
        }
        float eq[4] = {0.f, 0.f, 0.f, 0.f};

        for (int tj = ti; tj < 4; ++tj) {
            const int m0 = tj * 64 + mm * 2;
            const int sw = (m0 >> 2) & 7;              // same for m0, m0+1
            U8 p0, p1;
            p0.f4[0] = ((const float4*)rows)[(m0 * 2) ^ sw];
            p0.f4[1] = ((const float4*)rows)[(m0 * 2 + 1) ^ sw];
            p1.f4[0] = ((const float4*)rows)[(m0 * 2 + 2) ^ sw];
            p1.f4[1] = ((const float4*)rows)[(m0 * 2 + 3) ^ sw];

            float pm0 = 0.f, pm1 = 0.f;
            #pragma unroll
            for (int r = 0; r < 4; ++r) {
                float a0 = 0.f, a1 = 0.f, b0 = 0.f, b1 = 0.f;
                #pragma unroll
                for (int i = 0; i < 8; i += 2) {
                    h2 d0 = q[r].h[i] - p0.h[i];
                    h2 d1 = q[r].h[i + 1] - p0.h[i + 1];
                    h2 d2 = q[r].h[i] - p1.h[i];
                    h2 d3 = q[r].h[i + 1] - p1.h[i + 1];
                    unsigned u0 = (*(unsigned*)&d0) & 0x7FFF7FFFu;
                    unsigned u1 = (*(unsigned*)&d1) & 0x7FFF7FFFu;
                    unsigned u2 = (*(unsigned*)&d2) & 0x7FFF7FFFu;
                    unsigned u3 = (*(unsigned*)&d3) & 0x7FFF7FFFu;
                    a0 = __builtin_amdgcn_fdot2(*(h2*)&u0, one, a0, false);
                    a1 = __builtin_amdgcn_fdot2(*(h2*)&u1, one, a1, false);
                    b0 = __builtin_amdgcn_fdot2(*(h2*)&u2, one, b0, false);
                    b1 = __builtin_amdgcn_fdot2(*(h2*)&u3, one, b1, false);
                }
                const float e0 = __expf(-(a0 + a1));
                const float e1 = __expf(-(b0 + b1));
                eq[r] += e0 + e1;
                pm0 += e0;
                pm1 += e1;
            }
            if (tj > ti) {
                // m-side: reduce over qq (16 lanes), leader accumulates into Sm.
                #pragma unroll
                for (int s = 1; s < 16; s <<= 1) {
                    pm0 += __shfl_xor(pm0, s);
                    pm1 += __shfl_xor(pm1, s);
                }
                if (qq == 0) {          // thread mm*16: unique owner of Sm[m0], Sm[m0+1]
                    Sm[m0] += pm0;
                    Sm[m0 + 1] += pm1;
                }
            }
        }
        // q-side flush: reduce over this wave's 4 mm values, store per-wave partial
        #pragma unroll
        for (int r = 0; r < 4; ++r) {
            eq[r] += __shfl_xor(eq[r], 16);
            eq[r] += __shfl_xor(eq[r], 32);
        }
        if (lane < 16) {
            #pragma unroll
            for (int r = 0; r < 4; ++r)
                part[(ti * 64 + lane * 4 + r) * 8 + w] = eq[r];
        }
    }
    __syncthreads();

    if (t < NB) {
        const float* pp = &part[t * 8];
        float s = Sm[t] - 1.f;   // remove self term exp(0)=1 (counted in diag tile)
        #pragma unroll
        for (int i = 0; i < 8; ++i) s += pp[i];
        out[(size_t)t * OUT_F + IN_F + b] = s;
    }
}

extern "C" void kernel_launch(void* const* d_in, const int* in_sizes, int n_in,
                              void* d_out, int out_size, void* d_ws, size_t ws_size,
                              hipStream_t stream) {
    const float* x = (const float*)d_in[0];   // (256, 1024)
    const float* T = (const float*)d_in[1];   // (1024, 4096)
    float* out = (float*)d_out;               // (256, 1280)

    char* ws = (char*)d_ws;
    unsigned short* x_bf = (unsigned short*)ws;                        // 512 KB
    unsigned short* Tt   = (unsigned short*)(ws + (1u << 19));         // 8 MB
    __half* M2h          = (__half*)(ws + (1u << 19) + (1u << 23));    // 2 MB

    k_prep<<<dim3(4352), dim3(256), 0, stream>>>(x, T, out, x_bf, Tt);
    k_gemm<<<dim3(64, 4), dim3(256), 0, stream>>>(x_bf, Tt, M2h);
    k_pairwise<<<dim3(256), dim3(512), 0, stream>>>(M2h, out);
}